// Round 2
// 1055.884 us; speedup vs baseline: 1.0757x; 1.0757x over previous
//
#include <hip/hip_runtime.h>

#define CH 64

using bf16x8 = __attribute__((ext_vector_type(8))) short;
using f32x4  = __attribute__((ext_vector_type(4))) float;

__device__ __forceinline__ unsigned short f2bf(float f) {
  unsigned int u = __float_as_uint(f);
  u = (u + 0x7FFFu + ((u >> 16) & 1u)) >> 16;
  return (unsigned short)u;
}

__device__ __forceinline__ bf16x8 pack8(f32x4 a, f32x4 b) {
  bf16x8 r;
  r[0] = (short)f2bf(a[0]); r[1] = (short)f2bf(a[1]);
  r[2] = (short)f2bf(a[2]); r[3] = (short)f2bf(a[3]);
  r[4] = (short)f2bf(b[0]); r[5] = (short)f2bf(b[1]);
  r[6] = (short)f2bf(b[2]); r[7] = (short)f2bf(b[3]);
  return r;
}

// ---- padded strides (ushort elements)
#define E0S 200   // K=192+8
#define S64 72    // K=64+8
#define N0S 136   // K=128+8

// ---- edge kernel LDS layout (ushort offsets) ----
#define EW0_L 0        // [64][200]
#define EW1_L 12800    // [64][72]
#define EW2_L 17408    // [64][72]
#define EW_TOT 22016
// h1 scratch: per-wave [16][72] at EW_TOT + wave*1152 (8 waves)
#define E_LDS 31232    // 62464 B -> 2 blocks/CU at 512 threads

// ---- node kernel LDS layout ----
#define NW0_L 0
#define NW1_L 8704
#define NW2_L 13312
#define NW_TOT 17920
// h1 scratch: per-wave [16][72] at NW_TOT + wave*1152 (4 waves)
#define N_LDS 22528    // 45056 B -> 3 blocks/CU at 256 threads

// ---- ws layout (bytes) ----
#define WS_NW 66048            // ushort offset of node weights
#define WS_AGG_B    262144
#define WS_ROWPTR_B 13062144
#define WS_NEXT_B   13262208
#define WS_EID_B    13462208

// ================= weight prep: f32 -> transposed padded bf16 =================
__global__ void prep_w(const float* __restrict__ ew0, const float* __restrict__ ew1,
                       const float* __restrict__ ew2, const float* __restrict__ nw0,
                       const float* __restrict__ nw1, const float* __restrict__ nw2,
                       unsigned short* __restrict__ ws) {
  int i = blockIdx.x * 256 + threadIdx.x;
  if (i < 36864) {                       // ew0: (L,192,64)
    int l = i / 12288, r = i % 12288, k = r / 64, n = r % 64;
    ws[l * EW_TOT + EW0_L + n * E0S + k] = f2bf(ew0[i]);
  } else if (i < 49152) {                // ew1: (L,64,64)
    int j = i - 36864, l = j / 4096, r = j % 4096, k = r / 64, n = r % 64;
    ws[l * EW_TOT + EW1_L + n * S64 + k] = f2bf(ew1[j]);
  } else if (i < 61440) {                // ew2
    int j = i - 49152, l = j / 4096, r = j % 4096, k = r / 64, n = r % 64;
    ws[l * EW_TOT + EW2_L + n * S64 + k] = f2bf(ew2[j]);
  } else if (i < 86016) {                // nw0: (L,128,64)
    int j = i - 61440, l = j / 8192, r = j % 8192, k = r / 64, n = r % 64;
    ws[WS_NW + l * NW_TOT + NW0_L + n * N0S + k] = f2bf(nw0[j]);
  } else if (i < 98304) {                // nw1
    int j = i - 86016, l = j / 4096, r = j % 4096, k = r / 64, n = r % 64;
    ws[WS_NW + l * NW_TOT + NW1_L + n * S64 + k] = f2bf(nw1[j]);
  } else if (i < 110592) {               // nw2
    int j = i - 98304, l = j / 4096, r = j % 4096, k = r / 64, n = r % 64;
    ws[WS_NW + l * NW_TOT + NW2_L + n * S64 + k] = f2bf(nw2[j]);
  }
}

// ================= CSR build =================
__global__ void hist_k(const int* __restrict__ dst, int* __restrict__ counts, int nE) {
  int i = blockIdx.x * 256 + threadIdx.x;
  if (i < nE) atomicAdd(counts + dst[i], 1);
}

// single block, 1024 threads; counts may alias `next`
__global__ void scan_k(const int* __restrict__ counts, int* __restrict__ row_ptr,
                       int* __restrict__ next, int n) {
  __shared__ int wsum[16];
  __shared__ int chunk_tot;
  __shared__ int base_sh;
  const int tid = threadIdx.x, lane = tid & 63, wv = tid >> 6;
  if (tid == 0) { base_sh = 0; row_ptr[0] = 0; }
  __syncthreads();
  for (int start = 0; start < n; start += 4096) {
    int idx = start + tid * 4;
    int v[4], s = 0;
#pragma unroll
    for (int k = 0; k < 4; ++k) { v[k] = (idx + k < n) ? counts[idx + k] : 0; s += v[k]; }
    int incl = s;
#pragma unroll
    for (int off = 1; off < 64; off <<= 1) {
      int t = __shfl_up(incl, off, 64);
      if (lane >= off) incl += t;
    }
    if (lane == 63) wsum[wv] = incl;
    __syncthreads();
    if (wv == 0 && lane < 16) {
      int w = wsum[lane];
      int wincl = w;
#pragma unroll
      for (int off = 1; off < 16; off <<= 1) {
        int t = __shfl_up(wincl, off, 16);
        if (lane >= off) wincl += t;
      }
      if (lane == 15) chunk_tot = wincl;
      wsum[lane] = wincl - w;   // exclusive over waves
    }
    __syncthreads();
    int run = base_sh + wsum[wv] + (incl - s);
#pragma unroll
    for (int k = 0; k < 4; ++k) {
      int i = idx + k;
      if (i < n) { next[i] = run; run += v[k]; row_ptr[i + 1] = run; }
    }
    __syncthreads();
    if (tid == 0) base_sh += chunk_tot;
    __syncthreads();
  }
}

__global__ void scatter_k(const int* __restrict__ dst, int* __restrict__ next,
                          int* __restrict__ eid, int nE) {
  int i = blockIdx.x * 256 + threadIdx.x;
  if (i < nE) {
    int p = atomicAdd(next + dst[i], 1);
    eid[p] = i;
  }
}

// ================= edge kernel =================
// 512 threads (8 waves), direct global->register A-fragment gather (no h0 LDS),
// single per-wave h1 scratch reused by both inter-stage activations.
__global__ __launch_bounds__(512, 4)
void edge_kernel(const float* __restrict__ x, const float* e_in, float* e_out,
                 const int* __restrict__ src, const int* __restrict__ dst,
                 const unsigned short* __restrict__ wg,
                 const float* __restrict__ b0, const float* __restrict__ b1,
                 const float* __restrict__ b2, const float* __restrict__ gam,
                 const float* __restrict__ bet, int nE) {
  __shared__ unsigned short lds[E_LDS];
  const int tid = threadIdx.x;
  {
    const uint4* s4 = (const uint4*)wg;
    uint4* d4 = (uint4*)lds;
    for (int i = tid; i < EW_TOT / 8; i += 512) d4[i] = s4[i];
  }
  __syncthreads();

  const int wave = tid >> 6, lane = tid & 63;
  const int quad = lane >> 4, l15 = lane & 15;
  const int h1o = EW_TOT + wave * 1152;

  float b0c[4], b1c[4], b2c[4], gc[4], btc[4];
#pragma unroll
  for (int j = 0; j < 4; ++j) {
    int col = j * 16 + l15;
    b0c[j] = b0[col]; b1c[j] = b1[col]; b2c[j] = b2[col];
    gc[j] = gam[col]; btc[j] = bet[col];
  }

  const int o1 = quad * 8, o2 = 32 + quad * 8;

  for (int base = blockIdx.x * 128; base < nE; base += gridDim.x * 128) {
    const int ebase = base + wave * 16;
    const int row = ebase + l15;
    // ---- direct gather of A fragments: concat(x[src], x[dst], e) row `l15` ----
    int si = src[row], di = dst[row];
    const float* xs = x + (size_t)si * CH;
    const float* xd = x + (size_t)di * CH;
    const float* er = e_in + (size_t)row * CH;
    bf16x8 af[6];
    {
      f32x4 a0 = *(const f32x4*)(xs + o1);
      f32x4 a1 = *(const f32x4*)(xs + o1 + 4);
      f32x4 a2 = *(const f32x4*)(xs + o2);
      f32x4 a3 = *(const f32x4*)(xs + o2 + 4);
      af[0] = pack8(a0, a1); af[1] = pack8(a2, a3);
    }
    {
      f32x4 a0 = *(const f32x4*)(xd + o1);
      f32x4 a1 = *(const f32x4*)(xd + o1 + 4);
      f32x4 a2 = *(const f32x4*)(xd + o2);
      f32x4 a3 = *(const f32x4*)(xd + o2 + 4);
      af[2] = pack8(a0, a1); af[3] = pack8(a2, a3);
    }
    {
      f32x4 a0 = *(const f32x4*)(er + o1);
      f32x4 a1 = *(const f32x4*)(er + o1 + 4);
      f32x4 a2 = *(const f32x4*)(er + o2);
      f32x4 a3 = *(const f32x4*)(er + o2 + 4);
      af[4] = pack8(a0, a1); af[5] = pack8(a2, a3);
    }

    // ---- stage 0: [16x192] @ [192x64] ----
    f32x4 acc0[4];
#pragma unroll
    for (int j = 0; j < 4; ++j) acc0[j] = (f32x4){0.f, 0.f, 0.f, 0.f};
#pragma unroll
    for (int t = 0; t < 6; ++t) {
#pragma unroll
      for (int j = 0; j < 4; ++j) {
        bf16x8 b = *(const bf16x8*)(lds + EW0_L + (j * 16 + l15) * E0S + t * 32 + quad * 8);
        acc0[j] = __builtin_amdgcn_mfma_f32_16x16x32_bf16(af[t], b, acc0[j], 0, 0, 0);
      }
    }
#pragma unroll
    for (int j = 0; j < 4; ++j) {
      int col = j * 16 + l15;
#pragma unroll
      for (int r = 0; r < 4; ++r) {
        float v = fmaxf(acc0[j][r] + b0c[j], 0.f);
        lds[h1o + (quad * 4 + r) * S64 + col] = f2bf(v);
      }
    }
    // ---- stage 1 (reads h1, then overwrites h1 in place; per-wave DS is in-order) ----
    f32x4 acc1[4];
#pragma unroll
    for (int j = 0; j < 4; ++j) acc1[j] = (f32x4){0.f, 0.f, 0.f, 0.f};
#pragma unroll
    for (int t = 0; t < 2; ++t) {
      bf16x8 a = *(const bf16x8*)(lds + h1o + l15 * S64 + t * 32 + quad * 8);
#pragma unroll
      for (int j = 0; j < 4; ++j) {
        bf16x8 b = *(const bf16x8*)(lds + EW1_L + (j * 16 + l15) * S64 + t * 32 + quad * 8);
        acc1[j] = __builtin_amdgcn_mfma_f32_16x16x32_bf16(a, b, acc1[j], 0, 0, 0);
      }
    }
#pragma unroll
    for (int j = 0; j < 4; ++j) {
      int col = j * 16 + l15;
#pragma unroll
      for (int r = 0; r < 4; ++r) {
        float v = fmaxf(acc1[j][r] + b1c[j], 0.f);
        lds[h1o + (quad * 4 + r) * S64 + col] = f2bf(v);
      }
    }
    // ---- stage 2 ----
    f32x4 acc2[4];
#pragma unroll
    for (int j = 0; j < 4; ++j) acc2[j] = (f32x4){0.f, 0.f, 0.f, 0.f};
#pragma unroll
    for (int t = 0; t < 2; ++t) {
      bf16x8 a = *(const bf16x8*)(lds + h1o + l15 * S64 + t * 32 + quad * 8);
#pragma unroll
      for (int j = 0; j < 4; ++j) {
        bf16x8 b = *(const bf16x8*)(lds + EW2_L + (j * 16 + l15) * S64 + t * 32 + quad * 8);
        acc2[j] = __builtin_amdgcn_mfma_f32_16x16x32_bf16(a, b, acc2[j], 0, 0, 0);
      }
    }
    // ---- LayerNorm + residual ----
    float vv[4][4], s1[4], s2[4];
#pragma unroll
    for (int r = 0; r < 4; ++r) { s1[r] = 0.f; s2[r] = 0.f; }
#pragma unroll
    for (int j = 0; j < 4; ++j)
#pragma unroll
      for (int r = 0; r < 4; ++r) {
        float v = acc2[j][r] + b2c[j];
        vv[j][r] = v; s1[r] += v; s2[r] += v * v;
      }
#pragma unroll
    for (int m = 1; m < 16; m <<= 1)
#pragma unroll
      for (int r = 0; r < 4; ++r) {
        s1[r] += __shfl_xor(s1[r], m, 64);
        s2[r] += __shfl_xor(s2[r], m, 64);
      }
#pragma unroll
    for (int r = 0; r < 4; ++r) {
      int eidx = ebase + quad * 4 + r;
      float mean = s1[r] * 0.015625f;
      float var = s2[r] * 0.015625f - mean * mean;
      float rstd = rsqrtf(var + 1e-5f);
      const float* ein_row = e_in + (size_t)eidx * CH;
      float* eout_row = e_out + (size_t)eidx * CH;
#pragma unroll
      for (int j = 0; j < 4; ++j) {
        int col = j * 16 + l15;
        float y = (vv[j][r] - mean) * rstd * gc[j] + btc[j];
        eout_row[col] = ein_row[col] + y;
      }
    }
  }
}

// ================= gather aggregation (CSR), float4/lane =================
__global__ __launch_bounds__(256)
void agg_kernel(const float* __restrict__ e, const int* __restrict__ row_ptr,
                const int* __restrict__ eid, float* __restrict__ agg, int nN) {
  int node = blockIdx.x * 4 + (threadIdx.x >> 6);
  if (node >= nN) return;
  int lane = threadIdx.x & 63;
  int quad = lane >> 4, l15 = lane & 15;
  int r0 = row_ptr[node], r1 = row_ptr[node + 1];
  f32x4 s = (f32x4){0.f, 0.f, 0.f, 0.f};
  f32x4 s2 = (f32x4){0.f, 0.f, 0.f, 0.f};
  int i = r0 + quad;
  for (; i + 4 < r1; i += 8) {
    int e0 = eid[i], e1 = eid[i + 4];
    f32x4 a = *(const f32x4*)(e + (size_t)e0 * CH + l15 * 4);
    f32x4 b = *(const f32x4*)(e + (size_t)e1 * CH + l15 * 4);
    s += a; s2 += b;
  }
  for (; i < r1; i += 4) {
    int e0 = eid[i];
    s += *(const f32x4*)(e + (size_t)e0 * CH + l15 * 4);
  }
  s += s2;
#pragma unroll
  for (int c = 0; c < 4; ++c) {
    s[c] += __shfl_xor(s[c], 16, 64);
    s[c] += __shfl_xor(s[c], 32, 64);
  }
  if (quad == 0) *(f32x4*)(agg + (size_t)node * CH + l15 * 4) = s;
}

// ================= node kernel =================
// 256 threads, direct register gather (rows are contiguous), grid-stride,
// single per-wave h1 scratch. LDS 45056 B -> 3 blocks/CU.
__global__ __launch_bounds__(256, 3)
void node_kernel(const float* x_in, const float* __restrict__ agg_in,
                 const unsigned short* __restrict__ wg,
                 const float* __restrict__ b0, const float* __restrict__ b1,
                 const float* __restrict__ b2, const float* __restrict__ gam,
                 const float* __restrict__ bet, float* x_out, int nN) {
  __shared__ unsigned short lds[N_LDS];
  const int tid = threadIdx.x;
  {
    const uint4* s4 = (const uint4*)wg;
    uint4* d4 = (uint4*)lds;
    for (int i = tid; i < NW_TOT / 8; i += 256) d4[i] = s4[i];
  }
  __syncthreads();

  const int wave = tid >> 6, lane = tid & 63;
  const int quad = lane >> 4, l15 = lane & 15;
  const int h1o = NW_TOT + wave * 1152;

  float b0c[4], b1c[4], b2c[4], gc[4], btc[4];
#pragma unroll
  for (int j = 0; j < 4; ++j) {
    int col = j * 16 + l15;
    b0c[j] = b0[col]; b1c[j] = b1[col]; b2c[j] = b2[col];
    gc[j] = gam[col]; btc[j] = bet[col];
  }

  const int o1 = quad * 8, o2 = 32 + quad * 8;

  for (int base = blockIdx.x * 64; base < nN; base += gridDim.x * 64) {
    const int nbase = base + wave * 16;
    if (nbase >= nN) continue;
    const int row = nbase + l15;
    const float* xr = x_in + (size_t)row * CH;
    const float* ar = agg_in + (size_t)row * CH;
    bf16x8 af[4];
    {
      f32x4 a0 = *(const f32x4*)(xr + o1);
      f32x4 a1 = *(const f32x4*)(xr + o1 + 4);
      f32x4 a2 = *(const f32x4*)(xr + o2);
      f32x4 a3 = *(const f32x4*)(xr + o2 + 4);
      af[0] = pack8(a0, a1); af[1] = pack8(a2, a3);
    }
    {
      f32x4 a0 = *(const f32x4*)(ar + o1);
      f32x4 a1 = *(const f32x4*)(ar + o1 + 4);
      f32x4 a2 = *(const f32x4*)(ar + o2);
      f32x4 a3 = *(const f32x4*)(ar + o2 + 4);
      af[2] = pack8(a0, a1); af[3] = pack8(a2, a3);
    }

    f32x4 acc0[4];
#pragma unroll
    for (int j = 0; j < 4; ++j) acc0[j] = (f32x4){0.f, 0.f, 0.f, 0.f};
#pragma unroll
    for (int t = 0; t < 4; ++t) {
#pragma unroll
      for (int j = 0; j < 4; ++j) {
        bf16x8 b = *(const bf16x8*)(lds + NW0_L + (j * 16 + l15) * N0S + t * 32 + quad * 8);
        acc0[j] = __builtin_amdgcn_mfma_f32_16x16x32_bf16(af[t], b, acc0[j], 0, 0, 0);
      }
    }
#pragma unroll
    for (int j = 0; j < 4; ++j) {
      int col = j * 16 + l15;
#pragma unroll
      for (int r = 0; r < 4; ++r) {
        float v = fmaxf(acc0[j][r] + b0c[j], 0.f);
        lds[h1o + (quad * 4 + r) * S64 + col] = f2bf(v);
      }
    }
    f32x4 acc1[4];
#pragma unroll
    for (int j = 0; j < 4; ++j) acc1[j] = (f32x4){0.f, 0.f, 0.f, 0.f};
#pragma unroll
    for (int t = 0; t < 2; ++t) {
      bf16x8 a = *(const bf16x8*)(lds + h1o + l15 * S64 + t * 32 + quad * 8);
#pragma unroll
      for (int j = 0; j < 4; ++j) {
        bf16x8 b = *(const bf16x8*)(lds + NW1_L + (j * 16 + l15) * S64 + t * 32 + quad * 8);
        acc1[j] = __builtin_amdgcn_mfma_f32_16x16x32_bf16(a, b, acc1[j], 0, 0, 0);
      }
    }
#pragma unroll
    for (int j = 0; j < 4; ++j) {
      int col = j * 16 + l15;
#pragma unroll
      for (int r = 0; r < 4; ++r) {
        float v = fmaxf(acc1[j][r] + b1c[j], 0.f);
        lds[h1o + (quad * 4 + r) * S64 + col] = f2bf(v);
      }
    }
    f32x4 acc2[4];
#pragma unroll
    for (int j = 0; j < 4; ++j) acc2[j] = (f32x4){0.f, 0.f, 0.f, 0.f};
#pragma unroll
    for (int t = 0; t < 2; ++t) {
      bf16x8 a = *(const bf16x8*)(lds + h1o + l15 * S64 + t * 32 + quad * 8);
#pragma unroll
      for (int j = 0; j < 4; ++j) {
        bf16x8 b = *(const bf16x8*)(lds + NW2_L + (j * 16 + l15) * S64 + t * 32 + quad * 8);
        acc2[j] = __builtin_amdgcn_mfma_f32_16x16x32_bf16(a, b, acc2[j], 0, 0, 0);
      }
    }
    float vv[4][4], s1[4], s2[4];
#pragma unroll
    for (int r = 0; r < 4; ++r) { s1[r] = 0.f; s2[r] = 0.f; }
#pragma unroll
    for (int j = 0; j < 4; ++j)
#pragma unroll
      for (int r = 0; r < 4; ++r) {
        float v = acc2[j][r] + b2c[j];
        vv[j][r] = v; s1[r] += v; s2[r] += v * v;
      }
#pragma unroll
    for (int m = 1; m < 16; m <<= 1)
#pragma unroll
      for (int r = 0; r < 4; ++r) {
        s1[r] += __shfl_xor(s1[r], m, 64);
        s2[r] += __shfl_xor(s2[r], m, 64);
      }
#pragma unroll
    for (int r = 0; r < 4; ++r) {
      int node = nbase + quad * 4 + r;
      float mean = s1[r] * 0.015625f;
      float var = s2[r] * 0.015625f - mean * mean;
      float rstd = rsqrtf(var + 1e-5f);
      const float* xin_row = x_in + (size_t)node * CH;
      float* xout_row = x_out + (size_t)node * CH;
#pragma unroll
      for (int j = 0; j < 4; ++j) {
        int col = j * 16 + l15;
        float y = (vv[j][r] - mean) * rstd * gc[j] + btc[j];
        xout_row[col] = xin_row[col] + y;
      }
    }
  }
}

// ================= launcher =================
extern "C" void kernel_launch(void* const* d_in, const int* in_sizes, int n_in,
                              void* d_out, int out_size, void* d_ws, size_t ws_size,
                              hipStream_t stream) {
  const float* x0 = (const float*)d_in[0];
  const float* e0 = (const float*)d_in[1];
  const int* ei  = (const int*)d_in[2];
  const float* ew0 = (const float*)d_in[3];
  const float* eb0 = (const float*)d_in[4];
  const float* ew1 = (const float*)d_in[5];
  const float* eb1 = (const float*)d_in[6];
  const float* ew2 = (const float*)d_in[7];
  const float* eb2 = (const float*)d_in[8];
  const float* eg  = (const float*)d_in[9];
  const float* ebt = (const float*)d_in[10];
  const float* nw0 = (const float*)d_in[11];
  const float* nb0 = (const float*)d_in[12];
  const float* nw1 = (const float*)d_in[13];
  const float* nb1 = (const float*)d_in[14];
  const float* nw2 = (const float*)d_in[15];
  const float* nb2 = (const float*)d_in[16];
  const float* ng  = (const float*)d_in[17];
  const float* nbt = (const float*)d_in[18];

  const int N = in_sizes[0] / CH;   // 50000
  const int E = in_sizes[1] / CH;   // 800000
  const int* src = ei;
  const int* dst = ei + E;

  float* xout = (float*)d_out;
  float* eout = (float*)d_out + (size_t)N * CH;

  unsigned short* wsu = (unsigned short*)d_ws;
  float* agg    = (float*)((char*)d_ws + WS_AGG_B);
  int* row_ptr  = (int*)((char*)d_ws + WS_ROWPTR_B);
  int* nxt      = (int*)((char*)d_ws + WS_NEXT_B);
  int* eid      = (int*)((char*)d_ws + WS_EID_B);

  prep_w<<<432, 256, 0, stream>>>(ew0, ew1, ew2, nw0, nw1, nw2, wsu);

  // CSR build (dst is constant across layers)
  hipMemsetAsync(nxt, 0, (size_t)N * sizeof(int), stream);
  hist_k<<<(E + 255) / 256, 256, 0, stream>>>(dst, nxt, E);
  scan_k<<<1, 1024, 0, stream>>>(nxt, row_ptr, nxt, N);
  scatter_k<<<(E + 255) / 256, 256, 0, stream>>>(dst, nxt, eid, E);

  for (int l = 0; l < 3; ++l) {
    const float* xin = (l == 0) ? x0 : xout;
    const float* einp = (l == 0) ? e0 : eout;
    edge_kernel<<<512, 512, 0, stream>>>(
        xin, einp, eout, src, dst, wsu + l * EW_TOT,
        eb0 + l * CH, eb1 + l * CH, eb2 + l * CH, eg + l * CH, ebt + l * CH, E);
    agg_kernel<<<(N + 3) / 4, 256, 0, stream>>>(eout, row_ptr, eid, agg, N);
    node_kernel<<<768, 256, 0, stream>>>(
        xin, agg, wsu + WS_NW + l * NW_TOT,
        nb0 + l * CH, nb1 + l * CH, nb2 + l * CH, ng + l * CH, nbt + l * CH,
        xout, N);
  }
}

// Round 3
// 969.870 us; speedup vs baseline: 1.1711x; 1.0887x over previous
//
#include <hip/hip_runtime.h>

#define CH 64

using bf16x8 = __attribute__((ext_vector_type(8))) short;
using f32x4  = __attribute__((ext_vector_type(4))) float;

__device__ __forceinline__ unsigned short f2bf(float f) {
  unsigned int u = __float_as_uint(f);
  u = (u + 0x7FFFu + ((u >> 16) & 1u)) >> 16;
  return (unsigned short)u;
}

__device__ __forceinline__ bf16x8 pack8(f32x4 a, f32x4 b) {
  bf16x8 r;
  r[0] = (short)f2bf(a[0]); r[1] = (short)f2bf(a[1]);
  r[2] = (short)f2bf(a[2]); r[3] = (short)f2bf(a[3]);
  r[4] = (short)f2bf(b[0]); r[5] = (short)f2bf(b[1]);
  r[6] = (short)f2bf(b[2]); r[7] = (short)f2bf(b[3]);
  return r;
}

// ---- padded strides
#define E0S 200   // K=192+8 (ushort)
#define S64 72    // K=64+8  (ushort)
#define N0S 136   // K=128+8 (ushort)
#define Y68 68    // f32 y-scratch row stride (floats)

// ---- edge kernel LDS layout (ushort offsets) ----
#define EW0_L 0        // [64][200]
#define EW1_L 12800    // [64][72]
#define EW2_L 17408    // [64][72]
#define EW_TOT 22016
// per-wave scratch: 2176 ushort (= [16][72] bf16 inter-stage OR [16][68] f32 y)
#define E_LDS 39424    // 22016 + 8*2176 -> 78848 B -> 2 blocks/CU at 512 thr

// ---- node kernel LDS layout ----
#define NW0_L 0
#define NW1_L 8704
#define NW2_L 13312
#define NW_TOT 17920
#define N_LDS 26624    // 17920 + 4*2176 -> 53248 B -> 3 blocks/CU at 256 thr

// ---- ws layout (bytes) ----
#define WS_NW 66048            // ushort offset of node weights
#define WS_AGG_B    262144
#define WS_ROWPTR_B 13062144
#define WS_NEXT_B   13262208
#define WS_EID_B    13462208

// ================= weight prep: f32 -> transposed padded bf16 =================
__global__ void prep_w(const float* __restrict__ ew0, const float* __restrict__ ew1,
                       const float* __restrict__ ew2, const float* __restrict__ nw0,
                       const float* __restrict__ nw1, const float* __restrict__ nw2,
                       unsigned short* __restrict__ ws) {
  int i = blockIdx.x * 256 + threadIdx.x;
  if (i < 36864) {                       // ew0: (L,192,64)
    int l = i / 12288, r = i % 12288, k = r / 64, n = r % 64;
    ws[l * EW_TOT + EW0_L + n * E0S + k] = f2bf(ew0[i]);
  } else if (i < 49152) {                // ew1: (L,64,64)
    int j = i - 36864, l = j / 4096, r = j % 4096, k = r / 64, n = r % 64;
    ws[l * EW_TOT + EW1_L + n * S64 + k] = f2bf(ew1[j]);
  } else if (i < 61440) {                // ew2
    int j = i - 49152, l = j / 4096, r = j % 4096, k = r / 64, n = r % 64;
    ws[l * EW_TOT + EW2_L + n * S64 + k] = f2bf(ew2[j]);
  } else if (i < 86016) {                // nw0: (L,128,64)
    int j = i - 61440, l = j / 8192, r = j % 8192, k = r / 64, n = r % 64;
    ws[WS_NW + l * NW_TOT + NW0_L + n * N0S + k] = f2bf(nw0[j]);
  } else if (i < 98304) {                // nw1
    int j = i - 86016, l = j / 4096, r = j % 4096, k = r / 64, n = r % 64;
    ws[WS_NW + l * NW_TOT + NW1_L + n * S64 + k] = f2bf(nw1[j]);
  } else if (i < 110592) {               // nw2
    int j = i - 98304, l = j / 4096, r = j % 4096, k = r / 64, n = r % 64;
    ws[WS_NW + l * NW_TOT + NW2_L + n * S64 + k] = f2bf(nw2[j]);
  }
}

// ================= CSR build =================
__global__ void hist_k(const int* __restrict__ dst, int* __restrict__ counts, int nE) {
  int i = blockIdx.x * 256 + threadIdx.x;
  if (i < nE) atomicAdd(counts + dst[i], 1);
}

// single block, 1024 threads; counts may alias `next`
__global__ void scan_k(const int* __restrict__ counts, int* __restrict__ row_ptr,
                       int* __restrict__ next, int n) {
  __shared__ int wsum[16];
  __shared__ int chunk_tot;
  __shared__ int base_sh;
  const int tid = threadIdx.x, lane = tid & 63, wv = tid >> 6;
  if (tid == 0) { base_sh = 0; row_ptr[0] = 0; }
  __syncthreads();
  for (int start = 0; start < n; start += 4096) {
    int idx = start + tid * 4;
    int v[4], s = 0;
#pragma unroll
    for (int k = 0; k < 4; ++k) { v[k] = (idx + k < n) ? counts[idx + k] : 0; s += v[k]; }
    int incl = s;
#pragma unroll
    for (int off = 1; off < 64; off <<= 1) {
      int t = __shfl_up(incl, off, 64);
      if (lane >= off) incl += t;
    }
    if (lane == 63) wsum[wv] = incl;
    __syncthreads();
    if (wv == 0 && lane < 16) {
      int w = wsum[lane];
      int wincl = w;
#pragma unroll
      for (int off = 1; off < 16; off <<= 1) {
        int t = __shfl_up(wincl, off, 16);
        if (lane >= off) wincl += t;
      }
      if (lane == 15) chunk_tot = wincl;
      wsum[lane] = wincl - w;   // exclusive over waves
    }
    __syncthreads();
    int run = base_sh + wsum[wv] + (incl - s);
#pragma unroll
    for (int k = 0; k < 4; ++k) {
      int i = idx + k;
      if (i < n) { next[i] = run; run += v[k]; row_ptr[i + 1] = run; }
    }
    __syncthreads();
    if (tid == 0) base_sh += chunk_tot;
    __syncthreads();
  }
}

__global__ void scatter_k(const int* __restrict__ dst, int* __restrict__ next,
                          int* __restrict__ eid, int nE) {
  int i = blockIdx.x * 256 + threadIdx.x;
  if (i < nE) {
    int p = atomicAdd(next + dst[i], 1);
    eid[p] = i;
  }
}

// ================= edge kernel =================
// 512 threads (8 waves). Direct register A-fragment gather; e_in row held in
// registers as residual; LN output transposed through f32 LDS scratch and
// stored with coalesced dwordx4. Next-tile indices preloaded.
__global__ __launch_bounds__(512, 4)
void edge_kernel(const float* __restrict__ x, const float* e_in, float* e_out,
                 const int* __restrict__ src, const int* __restrict__ dst,
                 const unsigned short* __restrict__ wg,
                 const float* __restrict__ b0, const float* __restrict__ b1,
                 const float* __restrict__ b2, const float* __restrict__ gam,
                 const float* __restrict__ bet, int nE) {
  __shared__ unsigned short lds[E_LDS];
  const int tid = threadIdx.x;
  {
    const uint4* s4 = (const uint4*)wg;
    uint4* d4 = (uint4*)lds;
    for (int i = tid; i < EW_TOT / 8; i += 512) d4[i] = s4[i];
  }
  __syncthreads();

  const int wave = tid >> 6, lane = tid & 63;
  const int quad = lane >> 4, l15 = lane & 15;
  const int EHo = EW_TOT + wave * 2176;   // per-wave scratch (ushort units)
  float* yb = (float*)(lds + EHo);        // f32 view of same scratch

  float b0c[4], b1c[4], b2c[4], gc[4], btc[4];
#pragma unroll
  for (int j = 0; j < 4; ++j) {
    int col = j * 16 + l15;
    b0c[j] = b0[col]; b1c[j] = b1[col]; b2c[j] = b2[col];
    gc[j] = gam[col]; btc[j] = bet[col];
  }

  const int o1 = quad * 8, o2 = 32 + quad * 8;
  const int gstride = gridDim.x * 128;

  // prologue: indices for first tile
  int row0 = blockIdx.x * 128 + wave * 16 + l15;
  int si = src[row0], di = dst[row0];

  for (int base = blockIdx.x * 128; base < nE; base += gstride) {
    const int row = base + wave * 16 + l15;
    // ---- e_in row (stream, also residual) + x gathers ----
    const float* er = e_in + (size_t)row * CH;
    f32x4 ve0 = *(const f32x4*)(er + o1);
    f32x4 ve1 = *(const f32x4*)(er + o1 + 4);
    f32x4 ve2 = *(const f32x4*)(er + o2);
    f32x4 ve3 = *(const f32x4*)(er + o2 + 4);
    const float* xs = x + (size_t)si * CH;
    const float* xd = x + (size_t)di * CH;
    bf16x8 af[6];
    {
      f32x4 a0 = *(const f32x4*)(xs + o1);
      f32x4 a1 = *(const f32x4*)(xs + o1 + 4);
      f32x4 a2 = *(const f32x4*)(xs + o2);
      f32x4 a3 = *(const f32x4*)(xs + o2 + 4);
      af[0] = pack8(a0, a1); af[1] = pack8(a2, a3);
    }
    {
      f32x4 a0 = *(const f32x4*)(xd + o1);
      f32x4 a1 = *(const f32x4*)(xd + o1 + 4);
      f32x4 a2 = *(const f32x4*)(xd + o2);
      f32x4 a3 = *(const f32x4*)(xd + o2 + 4);
      af[2] = pack8(a0, a1); af[3] = pack8(a2, a3);
    }
    af[4] = pack8(ve0, ve1); af[5] = pack8(ve2, ve3);

    // preload next tile's indices (hidden under GEMM chain)
    {
      int nbase = base + gstride;
      if (nbase < nE) {
        int nrow = nbase + wave * 16 + l15;
        si = src[nrow]; di = dst[nrow];
      }
    }

    // ---- stage 0: [16x192] @ [192x64] ----
    f32x4 acc0[4];
#pragma unroll
    for (int j = 0; j < 4; ++j) acc0[j] = (f32x4){0.f, 0.f, 0.f, 0.f};
#pragma unroll
    for (int t = 0; t < 6; ++t) {
#pragma unroll
      for (int j = 0; j < 4; ++j) {
        bf16x8 b = *(const bf16x8*)(lds + EW0_L + (j * 16 + l15) * E0S + t * 32 + quad * 8);
        acc0[j] = __builtin_amdgcn_mfma_f32_16x16x32_bf16(af[t], b, acc0[j], 0, 0, 0);
      }
    }
#pragma unroll
    for (int j = 0; j < 4; ++j) {
      int col = j * 16 + l15;
#pragma unroll
      for (int r = 0; r < 4; ++r) {
        float v = fmaxf(acc0[j][r] + b0c[j], 0.f);
        lds[EHo + (quad * 4 + r) * S64 + col] = f2bf(v);
      }
    }
    // ---- stage 1 (in-place scratch reuse; per-wave DS in-order) ----
    f32x4 acc1[4];
#pragma unroll
    for (int j = 0; j < 4; ++j) acc1[j] = (f32x4){0.f, 0.f, 0.f, 0.f};
#pragma unroll
    for (int t = 0; t < 2; ++t) {
      bf16x8 a = *(const bf16x8*)(lds + EHo + l15 * S64 + t * 32 + quad * 8);
#pragma unroll
      for (int j = 0; j < 4; ++j) {
        bf16x8 b = *(const bf16x8*)(lds + EW1_L + (j * 16 + l15) * S64 + t * 32 + quad * 8);
        acc1[j] = __builtin_amdgcn_mfma_f32_16x16x32_bf16(a, b, acc1[j], 0, 0, 0);
      }
    }
#pragma unroll
    for (int j = 0; j < 4; ++j) {
      int col = j * 16 + l15;
#pragma unroll
      for (int r = 0; r < 4; ++r) {
        float v = fmaxf(acc1[j][r] + b1c[j], 0.f);
        lds[EHo + (quad * 4 + r) * S64 + col] = f2bf(v);
      }
    }
    // ---- stage 2 ----
    f32x4 acc2[4];
#pragma unroll
    for (int j = 0; j < 4; ++j) acc2[j] = (f32x4){0.f, 0.f, 0.f, 0.f};
#pragma unroll
    for (int t = 0; t < 2; ++t) {
      bf16x8 a = *(const bf16x8*)(lds + EHo + l15 * S64 + t * 32 + quad * 8);
#pragma unroll
      for (int j = 0; j < 4; ++j) {
        bf16x8 b = *(const bf16x8*)(lds + EW2_L + (j * 16 + l15) * S64 + t * 32 + quad * 8);
        acc2[j] = __builtin_amdgcn_mfma_f32_16x16x32_bf16(a, b, acc2[j], 0, 0, 0);
      }
    }
    // ---- LayerNorm stats in C-layout ----
    float vv[4][4], s1[4], s2[4];
#pragma unroll
    for (int r = 0; r < 4; ++r) { s1[r] = 0.f; s2[r] = 0.f; }
#pragma unroll
    for (int j = 0; j < 4; ++j)
#pragma unroll
      for (int r = 0; r < 4; ++r) {
        float v = acc2[j][r] + b2c[j];
        vv[j][r] = v; s1[r] += v; s2[r] += v * v;
      }
#pragma unroll
    for (int m = 1; m < 16; m <<= 1)
#pragma unroll
      for (int r = 0; r < 4; ++r) {
        s1[r] += __shfl_xor(s1[r], m, 64);
        s2[r] += __shfl_xor(s2[r], m, 64);
      }
    // normalized y -> f32 LDS scratch (C-layout write)
#pragma unroll
    for (int r = 0; r < 4; ++r) {
      float mean = s1[r] * 0.015625f;
      float var = s2[r] * 0.015625f - mean * mean;
      float rstd = rsqrtf(var + 1e-5f);
#pragma unroll
      for (int j = 0; j < 4; ++j) {
        float y = (vv[j][r] - mean) * rstd * gc[j] + btc[j];
        yb[(quad * 4 + r) * Y68 + j * 16 + l15] = y;
      }
    }
    // row-layout readback + register residual + coalesced store
    f32x4 y0 = *(const f32x4*)(yb + l15 * Y68 + o1);
    f32x4 y1 = *(const f32x4*)(yb + l15 * Y68 + o1 + 4);
    f32x4 y2 = *(const f32x4*)(yb + l15 * Y68 + o2);
    f32x4 y3 = *(const f32x4*)(yb + l15 * Y68 + o2 + 4);
    float* eo = e_out + (size_t)row * CH;
    *(f32x4*)(eo + o1)     = ve0 + y0;
    *(f32x4*)(eo + o1 + 4) = ve1 + y1;
    *(f32x4*)(eo + o2)     = ve2 + y2;
    *(f32x4*)(eo + o2 + 4) = ve3 + y3;
  }
}

// ================= gather aggregation (CSR), float4/lane =================
__global__ __launch_bounds__(256)
void agg_kernel(const float* __restrict__ e, const int* __restrict__ row_ptr,
                const int* __restrict__ eid, float* __restrict__ agg, int nN) {
  int node = blockIdx.x * 4 + (threadIdx.x >> 6);
  if (node >= nN) return;
  int lane = threadIdx.x & 63;
  int quad = lane >> 4, l15 = lane & 15;
  int r0 = row_ptr[node], r1 = row_ptr[node + 1];
  f32x4 s = (f32x4){0.f, 0.f, 0.f, 0.f};
  f32x4 s2 = (f32x4){0.f, 0.f, 0.f, 0.f};
  int i = r0 + quad;
  for (; i + 4 < r1; i += 8) {
    int e0 = eid[i], e1 = eid[i + 4];
    f32x4 a = *(const f32x4*)(e + (size_t)e0 * CH + l15 * 4);
    f32x4 b = *(const f32x4*)(e + (size_t)e1 * CH + l15 * 4);
    s += a; s2 += b;
  }
  for (; i < r1; i += 4) {
    int e0 = eid[i];
    s += *(const f32x4*)(e + (size_t)e0 * CH + l15 * 4);
  }
  s += s2;
#pragma unroll
  for (int c = 0; c < 4; ++c) {
    s[c] += __shfl_xor(s[c], 16, 64);
    s[c] += __shfl_xor(s[c], 32, 64);
  }
  if (quad == 0) *(f32x4*)(agg + (size_t)node * CH + l15 * 4) = s;
}

// ================= node kernel =================
// 256 threads, register gather, x residual held in registers, LN via f32
// LDS transpose + coalesced stores. LDS 53248 B -> 3 blocks/CU.
__global__ __launch_bounds__(256, 3)
void node_kernel(const float* x_in, const float* __restrict__ agg_in,
                 const unsigned short* __restrict__ wg,
                 const float* __restrict__ b0, const float* __restrict__ b1,
                 const float* __restrict__ b2, const float* __restrict__ gam,
                 const float* __restrict__ bet, float* x_out, int nN) {
  __shared__ unsigned short lds[N_LDS];
  const int tid = threadIdx.x;
  {
    const uint4* s4 = (const uint4*)wg;
    uint4* d4 = (uint4*)lds;
    for (int i = tid; i < NW_TOT / 8; i += 256) d4[i] = s4[i];
  }
  __syncthreads();

  const int wave = tid >> 6, lane = tid & 63;
  const int quad = lane >> 4, l15 = lane & 15;
  const int NHo = NW_TOT + wave * 2176;
  float* yb = (float*)(lds + NHo);

  float b0c[4], b1c[4], b2c[4], gc[4], btc[4];
#pragma unroll
  for (int j = 0; j < 4; ++j) {
    int col = j * 16 + l15;
    b0c[j] = b0[col]; b1c[j] = b1[col]; b2c[j] = b2[col];
    gc[j] = gam[col]; btc[j] = bet[col];
  }

  const int o1 = quad * 8, o2 = 32 + quad * 8;

  for (int base = blockIdx.x * 64; base < nN; base += gridDim.x * 64) {
    const int nbase = base + wave * 16;
    if (nbase >= nN) continue;
    const int row = nbase + l15;
    const float* xr = x_in + (size_t)row * CH;
    const float* ar = agg_in + (size_t)row * CH;
    f32x4 vx0 = *(const f32x4*)(xr + o1);
    f32x4 vx1 = *(const f32x4*)(xr + o1 + 4);
    f32x4 vx2 = *(const f32x4*)(xr + o2);
    f32x4 vx3 = *(const f32x4*)(xr + o2 + 4);
    bf16x8 af[4];
    af[0] = pack8(vx0, vx1); af[1] = pack8(vx2, vx3);
    {
      f32x4 a0 = *(const f32x4*)(ar + o1);
      f32x4 a1 = *(const f32x4*)(ar + o1 + 4);
      f32x4 a2 = *(const f32x4*)(ar + o2);
      f32x4 a3 = *(const f32x4*)(ar + o2 + 4);
      af[2] = pack8(a0, a1); af[3] = pack8(a2, a3);
    }

    f32x4 acc0[4];
#pragma unroll
    for (int j = 0; j < 4; ++j) acc0[j] = (f32x4){0.f, 0.f, 0.f, 0.f};
#pragma unroll
    for (int t = 0; t < 4; ++t) {
#pragma unroll
      for (int j = 0; j < 4; ++j) {
        bf16x8 b = *(const bf16x8*)(lds + NW0_L + (j * 16 + l15) * N0S + t * 32 + quad * 8);
        acc0[j] = __builtin_amdgcn_mfma_f32_16x16x32_bf16(af[t], b, acc0[j], 0, 0, 0);
      }
    }
#pragma unroll
    for (int j = 0; j < 4; ++j) {
      int col = j * 16 + l15;
#pragma unroll
      for (int r = 0; r < 4; ++r) {
        float v = fmaxf(acc0[j][r] + b0c[j], 0.f);
        lds[NHo + (quad * 4 + r) * S64 + col] = f2bf(v);
      }
    }
    f32x4 acc1[4];
#pragma unroll
    for (int j = 0; j < 4; ++j) acc1[j] = (f32x4){0.f, 0.f, 0.f, 0.f};
#pragma unroll
    for (int t = 0; t < 2; ++t) {
      bf16x8 a = *(const bf16x8*)(lds + NHo + l15 * S64 + t * 32 + quad * 8);
#pragma unroll
      for (int j = 0; j < 4; ++j) {
        bf16x8 b = *(const bf16x8*)(lds + NW1_L + (j * 16 + l15) * S64 + t * 32 + quad * 8);
        acc1[j] = __builtin_amdgcn_mfma_f32_16x16x32_bf16(a, b, acc1[j], 0, 0, 0);
      }
    }
#pragma unroll
    for (int j = 0; j < 4; ++j) {
      int col = j * 16 + l15;
#pragma unroll
      for (int r = 0; r < 4; ++r) {
        float v = fmaxf(acc1[j][r] + b1c[j], 0.f);
        lds[NHo + (quad * 4 + r) * S64 + col] = f2bf(v);
      }
    }
    f32x4 acc2[4];
#pragma unroll
    for (int j = 0; j < 4; ++j) acc2[j] = (f32x4){0.f, 0.f, 0.f, 0.f};
#pragma unroll
    for (int t = 0; t < 2; ++t) {
      bf16x8 a = *(const bf16x8*)(lds + NHo + l15 * S64 + t * 32 + quad * 8);
#pragma unroll
      for (int j = 0; j < 4; ++j) {
        bf16x8 b = *(const bf16x8*)(lds + NW2_L + (j * 16 + l15) * S64 + t * 32 + quad * 8);
        acc2[j] = __builtin_amdgcn_mfma_f32_16x16x32_bf16(a, b, acc2[j], 0, 0, 0);
      }
    }
    float vv[4][4], s1[4], s2[4];
#pragma unroll
    for (int r = 0; r < 4; ++r) { s1[r] = 0.f; s2[r] = 0.f; }
#pragma unroll
    for (int j = 0; j < 4; ++j)
#pragma unroll
      for (int r = 0; r < 4; ++r) {
        float v = acc2[j][r] + b2c[j];
        vv[j][r] = v; s1[r] += v; s2[r] += v * v;
      }
#pragma unroll
    for (int m = 1; m < 16; m <<= 1)
#pragma unroll
      for (int r = 0; r < 4; ++r) {
        s1[r] += __shfl_xor(s1[r], m, 64);
        s2[r] += __shfl_xor(s2[r], m, 64);
      }
#pragma unroll
    for (int r = 0; r < 4; ++r) {
      float mean = s1[r] * 0.015625f;
      float var = s2[r] * 0.015625f - mean * mean;
      float rstd = rsqrtf(var + 1e-5f);
#pragma unroll
      for (int j = 0; j < 4; ++j) {
        float y = (vv[j][r] - mean) * rstd * gc[j] + btc[j];
        yb[(quad * 4 + r) * Y68 + j * 16 + l15] = y;
      }
    }
    f32x4 y0 = *(const f32x4*)(yb + l15 * Y68 + o1);
    f32x4 y1 = *(const f32x4*)(yb + l15 * Y68 + o1 + 4);
    f32x4 y2 = *(const f32x4*)(yb + l15 * Y68 + o2);
    f32x4 y3 = *(const f32x4*)(yb + l15 * Y68 + o2 + 4);
    float* xo = x_out + (size_t)row * CH;
    *(f32x4*)(xo + o1)     = vx0 + y0;
    *(f32x4*)(xo + o1 + 4) = vx1 + y1;
    *(f32x4*)(xo + o2)     = vx2 + y2;
    *(f32x4*)(xo + o2 + 4) = vx3 + y3;
  }
}

// ================= launcher =================
extern "C" void kernel_launch(void* const* d_in, const int* in_sizes, int n_in,
                              void* d_out, int out_size, void* d_ws, size_t ws_size,
                              hipStream_t stream) {
  const float* x0 = (const float*)d_in[0];
  const float* e0 = (const float*)d_in[1];
  const int* ei  = (const int*)d_in[2];
  const float* ew0 = (const float*)d_in[3];
  const float* eb0 = (const float*)d_in[4];
  const float* ew1 = (const float*)d_in[5];
  const float* eb1 = (const float*)d_in[6];
  const float* ew2 = (const float*)d_in[7];
  const float* eb2 = (const float*)d_in[8];
  const float* eg  = (const float*)d_in[9];
  const float* ebt = (const float*)d_in[10];
  const float* nw0 = (const float*)d_in[11];
  const float* nb0 = (const float*)d_in[12];
  const float* nw1 = (const float*)d_in[13];
  const float* nb1 = (const float*)d_in[14];
  const float* nw2 = (const float*)d_in[15];
  const float* nb2 = (const float*)d_in[16];
  const float* ng  = (const float*)d_in[17];
  const float* nbt = (const float*)d_in[18];

  const int N = in_sizes[0] / CH;   // 50000
  const int E = in_sizes[1] / CH;   // 800000
  const int* src = ei;
  const int* dst = ei + E;

  float* xout = (float*)d_out;
  float* eout = (float*)d_out + (size_t)N * CH;

  unsigned short* wsu = (unsigned short*)d_ws;
  float* agg    = (float*)((char*)d_ws + WS_AGG_B);
  int* row_ptr  = (int*)((char*)d_ws + WS_ROWPTR_B);
  int* nxt      = (int*)((char*)d_ws + WS_NEXT_B);
  int* eid      = (int*)((char*)d_ws + WS_EID_B);

  prep_w<<<432, 256, 0, stream>>>(ew0, ew1, ew2, nw0, nw1, nw2, wsu);

  // CSR build (dst is constant across layers)
  hipMemsetAsync(nxt, 0, (size_t)N * sizeof(int), stream);
  hist_k<<<(E + 255) / 256, 256, 0, stream>>>(dst, nxt, E);
  scan_k<<<1, 1024, 0, stream>>>(nxt, row_ptr, nxt, N);
  scatter_k<<<(E + 255) / 256, 256, 0, stream>>>(dst, nxt, eid, E);

  for (int l = 0; l < 3; ++l) {
    const float* xin = (l == 0) ? x0 : xout;
    const float* einp = (l == 0) ? e0 : eout;
    edge_kernel<<<512, 512, 0, stream>>>(
        xin, einp, eout, src, dst, wsu + l * EW_TOT,
        eb0 + l * CH, eb1 + l * CH, eb2 + l * CH, eg + l * CH, ebt + l * CH, E);
    agg_kernel<<<(N + 3) / 4, 256, 0, stream>>>(eout, row_ptr, eid, agg, N);
    node_kernel<<<782, 256, 0, stream>>>(
        xin, agg, wsu + WS_NW + l * NW_TOT,
        nb0 + l * CH, nb1 + l * CH, nb2 + l * CH, ng + l * CH, nbt + l * CH,
        xout, N);
  }
}